// Round 4
// baseline (1622.102 us; speedup 1.0000x reference)
//
#include <hip/hip_runtime.h>
#include <stdint.h>

#define T_STEPS 256
#define BATCH 64
#define DIM 1024
#define HID 1024
#define RANK 256
#define FOURH 4096
#define M1 (T_STEPS * BATCH) // 16384

typedef __bf16 bf16_t;
typedef bf16_t bf16x8 __attribute__((ext_vector_type(8)));
typedef float f32x4 __attribute__((ext_vector_type(4)));

union frag_cast { uint4 u; bf16x8 v; };
union b_cast { unsigned long long ll[2]; bf16x8 v; };

__device__ __forceinline__ bf16x8 load_frag(const unsigned short* p) {
  frag_cast c; c.u = *reinterpret_cast<const uint4*>(p); return c.v;
}
__device__ __forceinline__ unsigned short f2bf(float f) {
  union { float f; uint32_t u; } v; v.f = f;
  uint32_t u = v.u;
  return (unsigned short)((u + 0x7fffu + ((u >> 16) & 1u)) >> 16);
}
__device__ __forceinline__ float bf2f(unsigned short h) {
  union { uint32_t u; float f; } v; v.u = ((uint32_t)h) << 16; return v.f;
}
// Branch-free fast gates: v_exp + v_rcp (~1e-7 rel err, negligible vs bf16 noise).
__device__ __forceinline__ float fsig(float x) {
  return __builtin_amdgcn_rcpf(1.f + __expf(-x));
}
__device__ __forceinline__ float ftanh(float x) {
  return 1.f - 2.f * __builtin_amdgcn_rcpf(1.f + __expf(2.f * x));
}

// Pack a [K x N] logical B matrix (f32 source) into MFMA B-fragment layout:
// frag (kc, nt): lane l slot s holds B[kc*32 + (l>>4)*8 + s][nt*16 + (l&15)].
__global__ void k_pack(const float* __restrict__ src, unsigned short* __restrict__ dst,
                       int NT, int ld, int transposed) {
  int id = blockIdx.x * blockDim.x + threadIdx.x;
  int lane = id & 63;
  int fi = id >> 6; // kc*NT + nt
  int nt = fi % NT, kc = fi / NT;
  int k0 = kc * 32 + ((lane >> 4) * 8);
  int n  = nt * 16 + (lane & 15);
  unsigned short vals[8];
  if (transposed) {
    const float* p = src + (size_t)n * ld + k0;
#pragma unroll
    for (int s = 0; s < 8; ++s) vals[s] = f2bf(p[s]);
  } else {
#pragma unroll
    for (int s = 0; s < 8; ++s) vals[s] = f2bf(src[(size_t)(k0 + s) * ld + n]);
  }
  union { unsigned short u16[8]; uint4 u; } o;
#pragma unroll
  for (int s = 0; s < 8; ++s) o.u16[s] = vals[s];
  *reinterpret_cast<uint4*>(dst + (size_t)id * 8) = o.u;
}

// corr_x[j] = dia_x[j%H] - dot(u_x[j%H,:], w_x[j,:]);  bias[j] = b_x[j]+b_h[j]
__global__ void k_coef(const float* __restrict__ u_x, const float* __restrict__ w_x,
                       const float* __restrict__ dia_x,
                       const float* __restrict__ b_x, const float* __restrict__ b_h,
                       float* __restrict__ corr, float* __restrict__ bias) {
  int wv = threadIdx.x >> 6, lane = threadIdx.x & 63;
  int j = blockIdx.x * 4 + wv;
  int e = j & (HID - 1);
  const float* up = u_x + (size_t)e * RANK + lane * 4;
  const float* wp = w_x + (size_t)j * RANK + lane * 4;
  float s = up[0] * wp[0] + up[1] * wp[1] + up[2] * wp[2] + up[3] * wp[3];
#pragma unroll
  for (int off = 32; off > 0; off >>= 1) s += __shfl_xor(s, off, 64);
  if (lane == 0) {
    corr[j] = dia_x[e] - s;
    bias[j] = b_x[j] + b_h[j];
  }
}

// Tagged h-exchange init: word = (tag16 << 16) | bf16(h).
// buf0 holds h(0) with tag 0; buf1 gets sentinel tag 0xFFFF (!= any real tag).
__global__ void k_init(const float* __restrict__ h0, uint32_t* __restrict__ hbuf) {
  int i = blockIdx.x * blockDim.x + threadIdx.x; // exactly BATCH*HID threads
  hbuf[i] = (uint32_t)f2bf(h0[i]);          // tag 0 | h0
  hbuf[BATCH * HID + i] = 0xFFFF0000u;      // sentinel
}

// C[M x 64*gridDim.x] = A_f32[M x 32*KC] @ packB, store bf16.
// dia != null: C is AhT [j][d]; override C[j][d] = dia[d] when d == j % HID.
__global__ void k_gemm_a32(const float* __restrict__ A, int lda,
                           const unsigned short* __restrict__ packB, int NTtot,
                           int KC, unsigned short* __restrict__ C, int ldc,
                           const float* __restrict__ dia) {
  int w = threadIdx.x >> 6, lane = threadIdx.x & 63;
  int q = lane >> 4, ln = lane & 15;
  int m0 = blockIdx.y * 64, n0 = blockIdx.x * 64;
  int arow = m0 + w * 16 + ln;
  f32x4 acc[4] = {};
  for (int kc = 0; kc < KC; ++kc) {
    const float* ap = A + (size_t)arow * lda + kc * 32 + q * 8;
    float4 x0 = *reinterpret_cast<const float4*>(ap);
    float4 x1 = *reinterpret_cast<const float4*>(ap + 4);
    bf16x8 a;
    a[0] = (bf16_t)x0.x; a[1] = (bf16_t)x0.y; a[2] = (bf16_t)x0.z; a[3] = (bf16_t)x0.w;
    a[4] = (bf16_t)x1.x; a[5] = (bf16_t)x1.y; a[6] = (bf16_t)x1.z; a[7] = (bf16_t)x1.w;
#pragma unroll
    for (int nt = 0; nt < 4; ++nt) {
      bf16x8 b = load_frag(packB + ((size_t)(kc * NTtot + blockIdx.x * 4 + nt) * 64 + lane) * 8);
      acc[nt] = __builtin_amdgcn_mfma_f32_16x16x32_bf16(a, b, acc[nt], 0, 0, 0);
    }
  }
#pragma unroll
  for (int nt = 0; nt < 4; ++nt) {
    int ccol = n0 + nt * 16 + ln;
#pragma unroll
    for (int r = 0; r < 4; ++r) {
      int crow = m0 + w * 16 + q * 4 + r;
      float v = acc[nt][r];
      if (dia != nullptr && ccol == (crow & (HID - 1))) v = dia[ccol];
      C[(size_t)crow * ldc + ccol] = f2bf(v);
    }
  }
}

// Repack AhT [j][d] (bf16) into per-(cg,gate,kc) B-fragment layout for k_rec.
__global__ void k_packAh(const unsigned short* __restrict__ AhT, unsigned short* __restrict__ dst) {
  int id = blockIdx.x * blockDim.x + threadIdx.x;
  int lane = id & 63;
  int fi = id >> 6;        // (cg*4+g)*32 + kc
  int kc = fi & 31;
  int g  = (fi >> 5) & 3;
  int cg = fi >> 7;
  int j  = g * HID + cg * 16 + (lane & 15);
  int d0 = kc * 32 + ((lane >> 4) * 8);
  uint4 v = *reinterpret_cast<const uint4*>(AhT + (size_t)j * HID + d0);
  *reinterpret_cast<uint4*>(dst + (size_t)id * 8) = v;
}

// gx[m][j] = P[m,:] @ w_xT[:,j] + x[m][j%H]*corr[j] + bias[j], store bf16.
__global__ void k_gemm2(const unsigned short* __restrict__ P,
                        const unsigned short* __restrict__ packWx,
                        const float* __restrict__ x,
                        const float* __restrict__ corr, const float* __restrict__ bias,
                        unsigned short* __restrict__ gx) {
  int w = threadIdx.x >> 6, lane = threadIdx.x & 63;
  int q = lane >> 4, ln = lane & 15;
  int m0 = blockIdx.y * 64, n0 = blockIdx.x * 64;
  int arow = m0 + w * 16 + ln;
  f32x4 acc[4] = {};
#pragma unroll
  for (int kc = 0; kc < 8; ++kc) {
    bf16x8 a = load_frag(P + (size_t)arow * RANK + kc * 32 + q * 8);
#pragma unroll
    for (int nt = 0; nt < 4; ++nt) {
      bf16x8 b = load_frag(packWx + ((size_t)(kc * 256 + blockIdx.x * 4 + nt) * 64 + lane) * 8);
      acc[nt] = __builtin_amdgcn_mfma_f32_16x16x32_bf16(a, b, acc[nt], 0, 0, 0);
    }
  }
#pragma unroll
  for (int nt = 0; nt < 4; ++nt) {
    int j = n0 + nt * 16 + ln;
    int e = j & (HID - 1);
    float cj = corr[j], bj = bias[j];
#pragma unroll
    for (int r = 0; r < 4; ++r) {
      int m = m0 + w * 16 + q * 4 + r;
      float v = acc[nt][r] + x[(size_t)m * DIM + e] * cj + bj;
      gx[(size_t)m * FOURH + j] = f2bf(v);
    }
  }
}

// Persistent recurrent kernel — tag-in-data exchange, LDS-TRAFFIC optimized.
//  R3 post-mortem: step ~11.8k cy ≈ staging/poll 4k + LDS-scan 4k + epilogue
//  2k + visibility 2k. The LDS term = (#waves) x 32KB h-scan (every wave
//  must consume the full h tile). This version: 4 waves (not 8), each wave
//  = one gate x TWO 16-col units, so one A-frag LDS read feeds 2 MFMAs:
//   - LDS h-scan traffic halves (256 -> 128 KB/block-step); structural
//     2-way b128 conflicts halve (~35.6M -> ~17M expected).
//   - B fragments: 64/lane (1 KB) pinned in the unified VGPR/AGPR file;
//     waves_per_eu(1,1) gives the 512-reg budget (4 waves on 4 SIMDs).
//   - Retries now 16B sc1 loads too (R3 proved 16B observes fresh L3 data;
//     per-4B tags make torn reads harmless) -> half retry request cost.
//   - Epilogue: thread owns 2 adjacent h-elems -> publish is ONE 8B tagged
//     atomic store; tile[] LDS pass removed; pre[] stride 34 (<=2-way banks,
//     8B-aligned pair reads).
__global__ __launch_bounds__(256, 1) __attribute__((amdgpu_waves_per_eu(1, 1)))
void k_rec(
    const unsigned short* __restrict__ pAh,
    const unsigned short* __restrict__ gx,
    const float* __restrict__ c0,
    uint32_t* __restrict__ hbuf,   // [2][BATCH][HID] tagged words
    float* __restrict__ out) {
  const int tid = threadIdx.x;
  const int g = tid >> 6, lane = tid & 63;   // wave = gate g
  const int q = lane >> 4, ln = lane & 15;
  const int blk = blockIdx.x;
  const int cg2 = blk & 31, bg = blk >> 5;   // 32 col-blocks x 4 row-groups

  // Pin B fragments (2 units x 32 kc) via volatile 8B loads -> unified RF.
  unsigned long long bqa0[32], bqb0[32], bqa1[32], bqb1[32];
  {
    const unsigned long long* p0 = reinterpret_cast<const unsigned long long*>(pAh) +
        (((size_t)((2 * cg2 + 0) * 4 + g) * 32) * 64 + lane) * 2;
    const unsigned long long* p1 = reinterpret_cast<const unsigned long long*>(pAh) +
        (((size_t)((2 * cg2 + 1) * 4 + g) * 32) * 64 + lane) * 2;
#pragma unroll
    for (int kc = 0; kc < 32; ++kc) {
      bqa0[kc] = *reinterpret_cast<const volatile unsigned long long*>(p0 + (size_t)kc * 128);
      bqb0[kc] = *reinterpret_cast<const volatile unsigned long long*>(p0 + (size_t)kc * 128 + 1);
      bqa1[kc] = *reinterpret_cast<const volatile unsigned long long*>(p1 + (size_t)kc * 128);
      bqb1[kc] = *reinterpret_cast<const volatile unsigned long long*>(p1 + (size_t)kc * 128 + 1);
    }
  }

  // Epilogue ownership: thread -> (row rb, col pair 2*ec, 2*ec+1).
  const int rb = tid >> 4, ec = tid & 15;
  const int brow = bg * 16 + rb;
  const int e0 = cg2 * 32 + 2 * ec;
  float c_a = c0[brow * HID + e0];
  float c_b = c0[brow * HID + e0 + 1];

  __shared__ unsigned short hstage[16][1032];  // stride 2064B (16B-multiple)
  __shared__ float pre[4][16][34];             // stride 34: <=2-way, 8B-aligned pairs

  size_t g0 = (size_t)brow * FOURH;
  uint32_t gxv0 = *reinterpret_cast<const uint32_t*>(gx + g0 + e0);
  uint32_t gxv1 = *reinterpret_cast<const uint32_t*>(gx + g0 + HID + e0);
  uint32_t gxv2 = *reinterpret_cast<const uint32_t*>(gx + g0 + 2 * HID + e0);
  uint32_t gxv3 = *reinterpret_cast<const uint32_t*>(gx + g0 + 3 * HID + e0);

  for (int t = 0; t < T_STEPS; ++t) {
    const int cur = t & 1;
    const uint32_t* hb = hbuf + (size_t)cur * (BATCH * HID);
    const unsigned tagexp = (unsigned)t;

    // ---- Stage h(t): chunk i == row i; thread covers 16B granule tid. ----
    // All rounds use 16B sc1 loads; per-4B tags detect stale/torn chunks.
    uint4 rr[16];
    unsigned pend = 0xFFFFu;
    do {
#pragma unroll
      for (int i = 0; i < 16; ++i)
        if (pend & (1u << i)) {
          const uint32_t* p = hb + (((size_t)(bg * 16 + i)) << 10) + (tid << 2);
          asm volatile("global_load_dwordx4 %0, %1, off sc1"
                       : "=&v"(rr[i]) : "v"(p) : "memory");
        }
      asm volatile("s_waitcnt vmcnt(0)" ::: "memory");
      __builtin_amdgcn_sched_barrier(0);
#pragma unroll
      for (int i = 0; i < 16; ++i)
        if (pend & (1u << i)) {
          unsigned bad = ((rr[i].x >> 16) ^ tagexp) | ((rr[i].y >> 16) ^ tagexp) |
                         ((rr[i].z >> 16) ^ tagexp) | ((rr[i].w >> 16) ^ tagexp);
          if (bad == 0) {
            unsigned lo = (rr[i].x & 0xffffu) | (rr[i].y << 16);
            unsigned hi = (rr[i].z & 0xffffu) | (rr[i].w << 16);
            *reinterpret_cast<unsigned long long*>(&hstage[i][tid << 2]) =
                ((unsigned long long)hi << 32) | lo;
            pend &= ~(1u << i);
          }
        }
    } while (pend);
    __syncthreads();  // hstage ready

    // Prefetch gx(t+1); completes under the MFMA chain.
    const int tn = (t + 1 < T_STEPS) ? (t + 1) : t;
    const size_t gn = ((size_t)tn * BATCH + brow) * FOURH;
    uint32_t ngx0 = *reinterpret_cast<const uint32_t*>(gx + gn + e0);
    uint32_t ngx1 = *reinterpret_cast<const uint32_t*>(gx + gn + HID + e0);
    uint32_t ngx2 = *reinterpret_cast<const uint32_t*>(gx + gn + 2 * HID + e0);
    uint32_t ngx3 = *reinterpret_cast<const uint32_t*>(gx + gn + 3 * HID + e0);

    // MFMA: one A-frag read feeds BOTH col-units; 2 kc-parities = 4 chains.
    f32x4 acc00 = {}, acc01 = {}, acc10 = {}, acc11 = {};
#pragma unroll
    for (int kc = 0; kc < 32; kc += 2) {
      bf16x8 aA = load_frag(&hstage[ln][kc * 32 + q * 8]);
      bf16x8 aB = load_frag(&hstage[ln][(kc + 1) * 32 + q * 8]);
      b_cast b00, b01, b10, b11;
      b00.ll[0] = bqa0[kc];     b00.ll[1] = bqb0[kc];
      b01.ll[0] = bqa1[kc];     b01.ll[1] = bqb1[kc];
      b10.ll[0] = bqa0[kc + 1]; b10.ll[1] = bqb0[kc + 1];
      b11.ll[0] = bqa1[kc + 1]; b11.ll[1] = bqb1[kc + 1];
      acc00 = __builtin_amdgcn_mfma_f32_16x16x32_bf16(aA, b00.v, acc00, 0, 0, 0);
      acc01 = __builtin_amdgcn_mfma_f32_16x16x32_bf16(aA, b01.v, acc01, 0, 0, 0);
      acc10 = __builtin_amdgcn_mfma_f32_16x16x32_bf16(aB, b10.v, acc10, 0, 0, 0);
      acc11 = __builtin_amdgcn_mfma_f32_16x16x32_bf16(aB, b11.v, acc11, 0, 0, 0);
    }
#pragma unroll
    for (int r = 0; r < 4; ++r) {
      pre[g][q * 4 + r][ln]      = acc00[r] + acc10[r];
      pre[g][q * 4 + r][16 + ln] = acc01[r] + acc11[r];
    }
    __syncthreads();

    float2 p0 = *reinterpret_cast<const float2*>(&pre[0][rb][2 * ec]);
    float2 p1 = *reinterpret_cast<const float2*>(&pre[1][rb][2 * ec]);
    float2 p2 = *reinterpret_cast<const float2*>(&pre[2][rb][2 * ec]);
    float2 p3 = *reinterpret_cast<const float2*>(&pre[3][rb][2 * ec]);

    // Elem a (col e0)
    float ia = fsig(p0.x + bf2f((unsigned short)(gxv0 & 0xffffu)));
    float fa = fsig(p1.x + bf2f((unsigned short)(gxv1 & 0xffffu)));
    float oa = fsig(p2.x + bf2f((unsigned short)(gxv2 & 0xffffu)));
    float na = ftanh(p3.x + bf2f((unsigned short)(gxv3 & 0xffffu)));
    c_a = fa * c_a + ia * na;
    float hn_a = oa * ftanh(c_a);
    // Elem b (col e0+1)
    float ib = fsig(p0.y + bf2f((unsigned short)(gxv0 >> 16)));
    float fb = fsig(p1.y + bf2f((unsigned short)(gxv1 >> 16)));
    float ob = fsig(p2.y + bf2f((unsigned short)(gxv2 >> 16)));
    float nb = ftanh(p3.y + bf2f((unsigned short)(gxv3 >> 16)));
    c_b = fb * c_b + ib * nb;
    float hn_b = ob * ftanh(c_b);

    // Publish h(t+1): ONE 8B tagged relaxed agent atomic store per thread.
    {
      unsigned tg = ((unsigned)(t + 1)) << 16;
      unsigned long long wv =
          (unsigned long long)(tg | (unsigned)f2bf(hn_a)) |
          ((unsigned long long)(tg | (unsigned)f2bf(hn_b)) << 32);
      __hip_atomic_store(
          reinterpret_cast<unsigned long long*>(
              hbuf + (size_t)(cur ^ 1) * (BATCH * HID) + ((size_t)brow << 10) + e0),
          wv, __ATOMIC_RELAXED, __HIP_MEMORY_SCOPE_AGENT);
    }

    // out stores: never read on device; ack overlaps the next stage round.
    {
      float2 hv; hv.x = hn_a; hv.y = hn_b;
      *reinterpret_cast<float2*>(&out[((size_t)t * BATCH + brow) * HID + e0]) = hv;
      if (t == T_STEPS - 1) {
        float2 cv; cv.x = c_a; cv.y = c_b;
        *reinterpret_cast<float2*>(
            &out[(size_t)T_STEPS * BATCH * HID + brow * HID + e0]) = hv;       // h_f
        *reinterpret_cast<float2*>(
            &out[(size_t)T_STEPS * BATCH * HID + BATCH * HID + brow * HID + e0]) = cv; // c_f
      }
    }

    gxv0 = ngx0; gxv1 = ngx1; gxv2 = ngx2; gxv3 = ngx3;
  }
}

extern "C" void kernel_launch(void* const* d_in, const int* in_sizes, int n_in,
                              void* d_out, int out_size, void* d_ws, size_t ws_size,
                              hipStream_t stream) {
  const float* x     = (const float*)d_in[0];
  const float* h0    = (const float*)d_in[1];
  const float* c0    = (const float*)d_in[2];
  const float* u_x   = (const float*)d_in[3];
  const float* u_h   = (const float*)d_in[4];
  const float* w_x   = (const float*)d_in[5];
  const float* w_h   = (const float*)d_in[6];
  const float* b_x   = (const float*)d_in[7];
  const float* b_h   = (const float*)d_in[8];
  const float* dia_x = (const float*)d_in[9];
  const float* dia_h = (const float*)d_in[10];
  float* out = (float*)d_out;
  (void)in_sizes; (void)n_in; (void)out_size; (void)ws_size;

  char* base = (char*)d_ws;
  size_t off = 0;
  auto alloc = [&](size_t bytes) -> void* {
    void* p = base + off;
    off = (off + bytes + 255) & ~(size_t)255;
    return p;
  };
  unsigned short* pUx  = (unsigned short*)alloc((size_t)32 * 16 * 64 * 8 * 2);
  unsigned short* pUhT = (unsigned short*)alloc((size_t)8 * 64 * 64 * 8 * 2);
  unsigned short* pWx  = (unsigned short*)alloc((size_t)8 * 256 * 64 * 8 * 2);
  float* corr = (float*)alloc((size_t)FOURH * 4);
  float* bias = (float*)alloc((size_t)FOURH * 4);
  uint32_t* hbufT = (uint32_t*)alloc((size_t)2 * BATCH * HID * 4);  // tagged
  unsigned short* P    = (unsigned short*)alloc((size_t)M1 * RANK * 2);
  unsigned short* AhT  = (unsigned short*)alloc((size_t)FOURH * HID * 2);
  unsigned short* pAh  = (unsigned short*)alloc((size_t)64 * 4 * 32 * 64 * 8 * 2);
  unsigned short* gx   = (unsigned short*)alloc((size_t)M1 * FOURH * 2);

  // B-operand packs (one-time, reused by GEMMs / recurrence)
  k_pack<<<128, 256, 0, stream>>>(u_x, pUx, 16, RANK, 0);   // G1 B: u_x [1024 x 256]
  k_pack<<<128, 256, 0, stream>>>(u_h, pUhT, 64, RANK, 1);  // G3 B: u_hT [256 x 1024]
  k_pack<<<512, 256, 0, stream>>>(w_x, pWx, 256, RANK, 1);  // G2 B: w_xT [256 x 4096]
  k_coef<<<1024, 256, 0, stream>>>(u_x, w_x, dia_x, b_x, b_h, corr, bias);
  k_init<<<256, 256, 0, stream>>>(h0, hbufT);
  // G1: P[16384 x 256] = X @ u_x
  k_gemm_a32<<<dim3(4, 256), 256, 0, stream>>>(x, DIM, pUx, 16, 32, P, RANK, nullptr);
  // G3: AhT[4096 x 1024] = w_h @ u_hT, diagonal overridden with dia_h
  k_gemm_a32<<<dim3(16, 64), 256, 0, stream>>>(w_h, RANK, pUhT, 64, 8, AhT, HID, dia_h);
  k_packAh<<<2048, 256, 0, stream>>>(AhT, pAh);
  // G2: gx = P @ w_xT + x*corr + bias  (bf16)
  k_gemm2<<<dim3(64, 256), 256, 0, stream>>>(P, pWx, x, corr, bias, gx);
  // Persistent recurrence (tag-in-data, LDS-traffic optimized: 4 waves)
  k_rec<<<128, 256, 0, stream>>>(pAh, gx, c0, hbufT, out);
}

// Round 5
// 1380.307 us; speedup vs baseline: 1.1752x; 1.1752x over previous
//
#include <hip/hip_runtime.h>
#include <stdint.h>

#define T_STEPS 256
#define BATCH 64
#define DIM 1024
#define HID 1024
#define RANK 256
#define FOURH 4096
#define M1 (T_STEPS * BATCH) // 16384

typedef __bf16 bf16_t;
typedef bf16_t bf16x8 __attribute__((ext_vector_type(8)));
typedef float f32x4 __attribute__((ext_vector_type(4)));

union frag_cast { uint4 u; bf16x8 v; };
union b_cast { unsigned long long ll[2]; bf16x8 v; };

__device__ __forceinline__ bf16x8 load_frag(const unsigned short* p) {
  frag_cast c; c.u = *reinterpret_cast<const uint4*>(p); return c.v;
}
__device__ __forceinline__ unsigned short f2bf(float f) {
  union { float f; uint32_t u; } v; v.f = f;
  uint32_t u = v.u;
  return (unsigned short)((u + 0x7fffu + ((u >> 16) & 1u)) >> 16);
}
__device__ __forceinline__ float bf2f(unsigned short h) {
  union { uint32_t u; float f; } v; v.u = ((uint32_t)h) << 16; return v.f;
}
// Branch-free fast gates: v_exp + v_rcp (~1e-7 rel err, negligible vs bf16 noise).
__device__ __forceinline__ float fsig(float x) {
  return __builtin_amdgcn_rcpf(1.f + __expf(-x));
}
__device__ __forceinline__ float ftanh(float x) {
  return 1.f - 2.f * __builtin_amdgcn_rcpf(1.f + __expf(2.f * x));
}

// Pack a [K x N] logical B matrix (f32 source) into MFMA B-fragment layout:
// frag (kc, nt): lane l slot s holds B[kc*32 + (l>>4)*8 + s][nt*16 + (l&15)].
__global__ void k_pack(const float* __restrict__ src, unsigned short* __restrict__ dst,
                       int NT, int ld, int transposed) {
  int id = blockIdx.x * blockDim.x + threadIdx.x;
  int lane = id & 63;
  int fi = id >> 6; // kc*NT + nt
  int nt = fi % NT, kc = fi / NT;
  int k0 = kc * 32 + ((lane >> 4) * 8);
  int n  = nt * 16 + (lane & 15);
  unsigned short vals[8];
  if (transposed) {
    const float* p = src + (size_t)n * ld + k0;
#pragma unroll
    for (int s = 0; s < 8; ++s) vals[s] = f2bf(p[s]);
  } else {
#pragma unroll
    for (int s = 0; s < 8; ++s) vals[s] = f2bf(src[(size_t)(k0 + s) * ld + n]);
  }
  union { unsigned short u16[8]; uint4 u; } o;
#pragma unroll
  for (int s = 0; s < 8; ++s) o.u16[s] = vals[s];
  *reinterpret_cast<uint4*>(dst + (size_t)id * 8) = o.u;
}

// corr_x[j] = dia_x[j%H] - dot(u_x[j%H,:], w_x[j,:]);  bias[j] = b_x[j]+b_h[j]
__global__ void k_coef(const float* __restrict__ u_x, const float* __restrict__ w_x,
                       const float* __restrict__ dia_x,
                       const float* __restrict__ b_x, const float* __restrict__ b_h,
                       float* __restrict__ corr, float* __restrict__ bias) {
  int wv = threadIdx.x >> 6, lane = threadIdx.x & 63;
  int j = blockIdx.x * 4 + wv;
  int e = j & (HID - 1);
  const float* up = u_x + (size_t)e * RANK + lane * 4;
  const float* wp = w_x + (size_t)j * RANK + lane * 4;
  float s = up[0] * wp[0] + up[1] * wp[1] + up[2] * wp[2] + up[3] * wp[3];
#pragma unroll
  for (int off = 32; off > 0; off >>= 1) s += __shfl_xor(s, off, 64);
  if (lane == 0) {
    corr[j] = dia_x[e] - s;
    bias[j] = b_x[j] + b_h[j];
  }
}

// Tagged h-exchange init: word = (tag16 << 16) | bf16(h).
// buf0 holds h(0) with tag 0; buf1 gets sentinel tag 0xFFFF (!= any real tag).
__global__ void k_init(const float* __restrict__ h0, uint32_t* __restrict__ hbuf) {
  int i = blockIdx.x * blockDim.x + threadIdx.x; // exactly BATCH*HID threads
  hbuf[i] = (uint32_t)f2bf(h0[i]);          // tag 0 | h0
  hbuf[BATCH * HID + i] = 0xFFFF0000u;      // sentinel
}

// C[M x 64*gridDim.x] = A_f32[M x 32*KC] @ packB, store bf16.
// dia != null: C is AhT [j][d]; override C[j][d] = dia[d] when d == j % HID.
__global__ void k_gemm_a32(const float* __restrict__ A, int lda,
                           const unsigned short* __restrict__ packB, int NTtot,
                           int KC, unsigned short* __restrict__ C, int ldc,
                           const float* __restrict__ dia) {
  int w = threadIdx.x >> 6, lane = threadIdx.x & 63;
  int q = lane >> 4, ln = lane & 15;
  int m0 = blockIdx.y * 64, n0 = blockIdx.x * 64;
  int arow = m0 + w * 16 + ln;
  f32x4 acc[4] = {};
  for (int kc = 0; kc < KC; ++kc) {
    const float* ap = A + (size_t)arow * lda + kc * 32 + q * 8;
    float4 x0 = *reinterpret_cast<const float4*>(ap);
    float4 x1 = *reinterpret_cast<const float4*>(ap + 4);
    bf16x8 a;
    a[0] = (bf16_t)x0.x; a[1] = (bf16_t)x0.y; a[2] = (bf16_t)x0.z; a[3] = (bf16_t)x0.w;
    a[4] = (bf16_t)x1.x; a[5] = (bf16_t)x1.y; a[6] = (bf16_t)x1.z; a[7] = (bf16_t)x1.w;
#pragma unroll
    for (int nt = 0; nt < 4; ++nt) {
      bf16x8 b = load_frag(packB + ((size_t)(kc * NTtot + blockIdx.x * 4 + nt) * 64 + lane) * 8);
      acc[nt] = __builtin_amdgcn_mfma_f32_16x16x32_bf16(a, b, acc[nt], 0, 0, 0);
    }
  }
#pragma unroll
  for (int nt = 0; nt < 4; ++nt) {
    int ccol = n0 + nt * 16 + ln;
#pragma unroll
    for (int r = 0; r < 4; ++r) {
      int crow = m0 + w * 16 + q * 4 + r;
      float v = acc[nt][r];
      if (dia != nullptr && ccol == (crow & (HID - 1))) v = dia[ccol];
      C[(size_t)crow * ldc + ccol] = f2bf(v);
    }
  }
}

// Repack AhT [j][d] (bf16) into per-(cg,gate,kc) B-fragment layout for k_rec.
__global__ void k_packAh(const unsigned short* __restrict__ AhT, unsigned short* __restrict__ dst) {
  int id = blockIdx.x * blockDim.x + threadIdx.x;
  int lane = id & 63;
  int fi = id >> 6;        // (cg*4+g)*32 + kc
  int kc = fi & 31;
  int g  = (fi >> 5) & 3;
  int cg = fi >> 7;
  int j  = g * HID + cg * 16 + (lane & 15);
  int d0 = kc * 32 + ((lane >> 4) * 8);
  uint4 v = *reinterpret_cast<const uint4*>(AhT + (size_t)j * HID + d0);
  *reinterpret_cast<uint4*>(dst + (size_t)id * 8) = v;
}

// gx[m][j] = P[m,:] @ w_xT[:,j] + x[m][j%H]*corr[j] + bias[j], store bf16.
__global__ void k_gemm2(const unsigned short* __restrict__ P,
                        const unsigned short* __restrict__ packWx,
                        const float* __restrict__ x,
                        const float* __restrict__ corr, const float* __restrict__ bias,
                        unsigned short* __restrict__ gx) {
  int w = threadIdx.x >> 6, lane = threadIdx.x & 63;
  int q = lane >> 4, ln = lane & 15;
  int m0 = blockIdx.y * 64, n0 = blockIdx.x * 64;
  int arow = m0 + w * 16 + ln;
  f32x4 acc[4] = {};
#pragma unroll
  for (int kc = 0; kc < 8; ++kc) {
    bf16x8 a = load_frag(P + (size_t)arow * RANK + kc * 32 + q * 8);
#pragma unroll
    for (int nt = 0; nt < 4; ++nt) {
      bf16x8 b = load_frag(packWx + ((size_t)(kc * 256 + blockIdx.x * 4 + nt) * 64 + lane) * 8);
      acc[nt] = __builtin_amdgcn_mfma_f32_16x16x32_bf16(a, b, acc[nt], 0, 0, 0);
    }
  }
#pragma unroll
  for (int nt = 0; nt < 4; ++nt) {
    int j = n0 + nt * 16 + ln;
    int e = j & (HID - 1);
    float cj = corr[j], bj = bias[j];
#pragma unroll
    for (int r = 0; r < 4; ++r) {
      int m = m0 + w * 16 + q * 4 + r;
      float v = acc[nt][r] + x[(size_t)m * DIM + e] * cj + bj;
      gx[(size_t)m * FOURH + j] = f2bf(v);
    }
  }
}

// X-macro lists for named-scalar B fragments (SROA-proof register pinning).
// R4 post-mortem: volatile-loaded ARRAYS (bqa[32] etc.) never scalarize ->
// scratch -> ~33.5 MB/step of L2 reload with dependent waits. VGPR_Count
// 96..200 across R0-R4 proves it. Named scalars are SSA values: the
// allocator can keep all 128 B-VGPRs resident (budget 256 @ 2 waves/EU).
#define KC_EACH(X) \
  X(0) X(1) X(2) X(3) X(4) X(5) X(6) X(7) \
  X(8) X(9) X(10) X(11) X(12) X(13) X(14) X(15) \
  X(16) X(17) X(18) X(19) X(20) X(21) X(22) X(23) \
  X(24) X(25) X(26) X(27) X(28) X(29) X(30) X(31)
// (kc, acc-chain kc%4) pairs for the MFMA loop.
#define KC_ACC(X) \
  X(0,0) X(1,1) X(2,2) X(3,3) X(4,0) X(5,1) X(6,2) X(7,3) \
  X(8,0) X(9,1) X(10,2) X(11,3) X(12,0) X(13,1) X(14,2) X(15,3) \
  X(16,0) X(17,1) X(18,2) X(19,3) X(20,0) X(21,1) X(22,2) X(23,3) \
  X(24,0) X(25,1) X(26,2) X(27,3) X(28,0) X(29,1) X(30,2) X(31,3)

// Persistent recurrent kernel — tag-in-data exchange with REGISTER-resident
// B fragments (named scalars). Geometry: 128 blocks x 512 threads (8 waves);
// wave w = (gate g = w&3, col-half ch2 = w>>2) -> 16-col unit
// cg_eff = cg2*2+ch2. Staging/poll/publish keep the R4-proven structure
// (all-16B sc1 rounds, per-4B tags, single 8B tagged publish per thread).
__global__ __launch_bounds__(512, 1) __attribute__((amdgpu_waves_per_eu(2, 2)))
void k_rec(
    const unsigned short* __restrict__ pAh,
    const unsigned short* __restrict__ gx,
    const float* __restrict__ c0,
    uint32_t* __restrict__ hbuf,   // [2][BATCH][HID] tagged words
    float* __restrict__ out) {
  const int tid = threadIdx.x;
  const int w = tid >> 6, lane = tid & 63;
  const int q = lane >> 4, ln = lane & 15;
  const int blk = blockIdx.x;
  const int cg2 = blk & 31, bg = blk >> 5;   // 32 col-blocks x 4 row-groups
  const int g = w & 3, ch2 = w >> 2;
  const int cg_eff = cg2 * 2 + ch2;

  // Pin B fragments: 64 NAMED u64 scalars, volatile-loaded once.
  const unsigned long long* pp = reinterpret_cast<const unsigned long long*>(pAh) +
                                 ((size_t)((cg_eff * 4 + g) * 32) * 64 + lane) * 2;
#define DECLB(k) unsigned long long BA_##k, BB_##k;
  KC_EACH(DECLB)
#undef DECLB
#define LOADB(k) \
  BA_##k = *reinterpret_cast<const volatile unsigned long long*>(pp + (size_t)(k) * 128); \
  BB_##k = *reinterpret_cast<const volatile unsigned long long*>(pp + (size_t)(k) * 128 + 1);
  KC_EACH(LOADB)
#undef LOADB

  // Epilogue ownership (tid<256): thread -> (row rb, col pair e0, e0+1).
  const int rb = (tid & 255) >> 4, ec = tid & 15;
  const int brow = bg * 16 + rb;
  const int e0 = cg2 * 32 + 2 * ec;
  float c_a = 0.f, c_b = 0.f;
  if (tid < 256) {
    c_a = c0[brow * HID + e0];
    c_b = c0[brow * HID + e0 + 1];
  }

  __shared__ unsigned short hstage[16][1032];  // stride 2064B (16B-multiple)
  __shared__ float pre[4][16][34];             // even stride: 8B-aligned pairs

  uint32_t gxv0 = 0, gxv1 = 0, gxv2 = 0, gxv3 = 0;
  if (tid < 256) {
    size_t g0 = (size_t)brow * FOURH;
    gxv0 = *reinterpret_cast<const uint32_t*>(gx + g0 + e0);
    gxv1 = *reinterpret_cast<const uint32_t*>(gx + g0 + HID + e0);
    gxv2 = *reinterpret_cast<const uint32_t*>(gx + g0 + 2 * HID + e0);
    gxv3 = *reinterpret_cast<const uint32_t*>(gx + g0 + 3 * HID + e0);
  }

  for (int t = 0; t < T_STEPS; ++t) {
    const int cur = t & 1;
    const uint32_t* hb = hbuf + (size_t)cur * (BATCH * HID);
    const unsigned tagexp = (unsigned)t;

    // ---- Stage h(t): 8 chunks/thread; all rounds 16B sc1; per-4B tags. ----
    // Chunk cc: ch = cc*512 + tid -> row = ch>>8, 16B-granule = ch&255.
    uint4 r0, r1, r2, r3, r4, r5, r6, r7;
    unsigned pend = 0xFFu;
    do {
#define ISSUE16(cc, rr)                                                        \
      if (pend & (1u << cc)) {                                                 \
        int ch = cc * 512 + tid;                                               \
        const uint32_t* p = hb + (((size_t)(bg * 16 + (ch >> 8))) << 10) +     \
                            ((ch & 255) << 2);                                 \
        asm volatile("global_load_dwordx4 %0, %1, off sc1"                     \
                     : "=&v"(rr) : "v"(p) : "memory");                         \
      }
      ISSUE16(0, r0) ISSUE16(1, r1) ISSUE16(2, r2) ISSUE16(3, r3)
      ISSUE16(4, r4) ISSUE16(5, r5) ISSUE16(6, r6) ISSUE16(7, r7)
#undef ISSUE16
      asm volatile("s_waitcnt vmcnt(0)" ::: "memory");
      __builtin_amdgcn_sched_barrier(0);
#define CHECK16(cc, rr)                                                        \
      if (pend & (1u << cc)) {                                                 \
        unsigned bad = ((rr.x >> 16) ^ tagexp) | ((rr.y >> 16) ^ tagexp) |     \
                       ((rr.z >> 16) ^ tagexp) | ((rr.w >> 16) ^ tagexp);      \
        if (bad == 0) {                                                        \
          int ch = cc * 512 + tid;                                             \
          unsigned lo = (rr.x & 0xffffu) | (rr.y << 16);                       \
          unsigned hi = (rr.z & 0xffffu) | (rr.w << 16);                       \
          *reinterpret_cast<unsigned long long*>(                              \
              &hstage[ch >> 8][(ch & 255) << 2]) =                             \
              ((unsigned long long)hi << 32) | lo;                             \
          pend &= ~(1u << cc);                                                 \
        }                                                                      \
      }
      CHECK16(0, r0) CHECK16(1, r1) CHECK16(2, r2) CHECK16(3, r3)
      CHECK16(4, r4) CHECK16(5, r5) CHECK16(6, r6) CHECK16(7, r7)
#undef CHECK16
    } while (pend);
    __syncthreads();  // hstage ready

    // Prefetch gx(t+1); completes under the MFMA chain.
    uint32_t ngx0 = 0, ngx1 = 0, ngx2 = 0, ngx3 = 0;
    if (tid < 256) {
      const int tn = (t + 1 < T_STEPS) ? (t + 1) : t;
      const size_t gn = ((size_t)tn * BATCH + brow) * FOURH;
      ngx0 = *reinterpret_cast<const uint32_t*>(gx + gn + e0);
      ngx1 = *reinterpret_cast<const uint32_t*>(gx + gn + HID + e0);
      ngx2 = *reinterpret_cast<const uint32_t*>(gx + gn + 2 * HID + e0);
      ngx3 = *reinterpret_cast<const uint32_t*>(gx + gn + 3 * HID + e0);
    }

    // MFMA: 32 kc, 4 independent acc chains, all B operands in registers.
    f32x4 acc0 = {}, acc1 = {}, acc2 = {}, acc3 = {};
#define MF(k, c) {                                                             \
      bf16x8 a = load_frag(&hstage[ln][(k) * 32 + q * 8]);                     \
      b_cast b; b.ll[0] = BA_##k; b.ll[1] = BB_##k;                            \
      acc##c = __builtin_amdgcn_mfma_f32_16x16x32_bf16(a, b.v, acc##c, 0, 0, 0); \
    }
    KC_ACC(MF)
#undef MF
#pragma unroll
    for (int r = 0; r < 4; ++r)
      pre[g][q * 4 + r][ch2 * 16 + ln] = (acc0[r] + acc1[r]) + (acc2[r] + acc3[r]);
    __syncthreads();

    if (tid < 256) {
      float2 p0 = *reinterpret_cast<const float2*>(&pre[0][rb][2 * ec]);
      float2 p1 = *reinterpret_cast<const float2*>(&pre[1][rb][2 * ec]);
      float2 p2 = *reinterpret_cast<const float2*>(&pre[2][rb][2 * ec]);
      float2 p3 = *reinterpret_cast<const float2*>(&pre[3][rb][2 * ec]);

      // Elem a (col e0)
      float ia = fsig(p0.x + bf2f((unsigned short)(gxv0 & 0xffffu)));
      float fa = fsig(p1.x + bf2f((unsigned short)(gxv1 & 0xffffu)));
      float oa = fsig(p2.x + bf2f((unsigned short)(gxv2 & 0xffffu)));
      float na = ftanh(p3.x + bf2f((unsigned short)(gxv3 & 0xffffu)));
      c_a = fa * c_a + ia * na;
      float hn_a = oa * ftanh(c_a);
      // Elem b (col e0+1)
      float ib = fsig(p0.y + bf2f((unsigned short)(gxv0 >> 16)));
      float fb = fsig(p1.y + bf2f((unsigned short)(gxv1 >> 16)));
      float ob = fsig(p2.y + bf2f((unsigned short)(gxv2 >> 16)));
      float nb = ftanh(p3.y + bf2f((unsigned short)(gxv3 >> 16)));
      c_b = fb * c_b + ib * nb;
      float hn_b = ob * ftanh(c_b);

      // Publish h(t+1): ONE 8B tagged relaxed agent atomic store per thread.
      unsigned tg = ((unsigned)(t + 1)) << 16;
      unsigned long long wv =
          (unsigned long long)(tg | (unsigned)f2bf(hn_a)) |
          ((unsigned long long)(tg | (unsigned)f2bf(hn_b)) << 32);
      __hip_atomic_store(
          reinterpret_cast<unsigned long long*>(
              hbuf + (size_t)(cur ^ 1) * (BATCH * HID) + ((size_t)brow << 10) + e0),
          wv, __ATOMIC_RELAXED, __HIP_MEMORY_SCOPE_AGENT);

      // out stores: never read on device; ack overlaps the next stage round.
      float2 hv; hv.x = hn_a; hv.y = hn_b;
      *reinterpret_cast<float2*>(&out[((size_t)t * BATCH + brow) * HID + e0]) = hv;
      if (t == T_STEPS - 1) {
        float2 cv; cv.x = c_a; cv.y = c_b;
        *reinterpret_cast<float2*>(
            &out[(size_t)T_STEPS * BATCH * HID + brow * HID + e0]) = hv;       // h_f
        *reinterpret_cast<float2*>(
            &out[(size_t)T_STEPS * BATCH * HID + BATCH * HID + brow * HID + e0]) = cv; // c_f
      }
      gxv0 = ngx0; gxv1 = ngx1; gxv2 = ngx2; gxv3 = ngx3;
    }
  }
}

extern "C" void kernel_launch(void* const* d_in, const int* in_sizes, int n_in,
                              void* d_out, int out_size, void* d_ws, size_t ws_size,
                              hipStream_t stream) {
  const float* x     = (const float*)d_in[0];
  const float* h0    = (const float*)d_in[1];
  const float* c0    = (const float*)d_in[2];
  const float* u_x   = (const float*)d_in[3];
  const float* u_h   = (const float*)d_in[4];
  const float* w_x   = (const float*)d_in[5];
  const float* w_h   = (const float*)d_in[6];
  const float* b_x   = (const float*)d_in[7];
  const float* b_h   = (const float*)d_in[8];
  const float* dia_x = (const float*)d_in[9];
  const float* dia_h = (const float*)d_in[10];
  float* out = (float*)d_out;
  (void)in_sizes; (void)n_in; (void)out_size; (void)ws_size;

  char* base = (char*)d_ws;
  size_t off = 0;
  auto alloc = [&](size_t bytes) -> void* {
    void* p = base + off;
    off = (off + bytes + 255) & ~(size_t)255;
    return p;
  };
  unsigned short* pUx  = (unsigned short*)alloc((size_t)32 * 16 * 64 * 8 * 2);
  unsigned short* pUhT = (unsigned short*)alloc((size_t)8 * 64 * 64 * 8 * 2);
  unsigned short* pWx  = (unsigned short*)alloc((size_t)8 * 256 * 64 * 8 * 2);
  float* corr = (float*)alloc((size_t)FOURH * 4);
  float* bias = (float*)alloc((size_t)FOURH * 4);
  uint32_t* hbufT = (uint32_t*)alloc((size_t)2 * BATCH * HID * 4);  // tagged
  unsigned short* P    = (unsigned short*)alloc((size_t)M1 * RANK * 2);
  unsigned short* AhT  = (unsigned short*)alloc((size_t)FOURH * HID * 2);
  unsigned short* pAh  = (unsigned short*)alloc((size_t)64 * 4 * 32 * 64 * 8 * 2);
  unsigned short* gx   = (unsigned short*)alloc((size_t)M1 * FOURH * 2);

  // B-operand packs (one-time, reused by GEMMs / recurrence)
  k_pack<<<128, 256, 0, stream>>>(u_x, pUx, 16, RANK, 0);   // G1 B: u_x [1024 x 256]
  k_pack<<<128, 256, 0, stream>>>(u_h, pUhT, 64, RANK, 1);  // G3 B: u_hT [256 x 1024]
  k_pack<<<512, 256, 0, stream>>>(w_x, pWx, 256, RANK, 1);  // G2 B: w_xT [256 x 4096]
  k_coef<<<1024, 256, 0, stream>>>(u_x, w_x, dia_x, b_x, b_h, corr, bias);
  k_init<<<256, 256, 0, stream>>>(h0, hbufT);
  // G1: P[16384 x 256] = X @ u_x
  k_gemm_a32<<<dim3(4, 256), 256, 0, stream>>>(x, DIM, pUx, 16, 32, P, RANK, nullptr);
  // G3: AhT[4096 x 1024] = w_h @ u_hT, diagonal overridden with dia_h
  k_gemm_a32<<<dim3(16, 64), 256, 0, stream>>>(w_h, RANK, pUhT, 64, 8, AhT, HID, dia_h);
  k_packAh<<<2048, 256, 0, stream>>>(AhT, pAh);
  // G2: gx = P @ w_xT + x*corr + bias  (bf16)
  k_gemm2<<<dim3(64, 256), 256, 0, stream>>>(P, pWx, x, corr, bias, gx);
  // Persistent recurrence (tag-in-data, named-register B fragments)
  k_rec<<<128, 512, 0, stream>>>(pAh, gx, c0, hbufT, out);
}